// Round 16
// baseline (123.640 us; speedup 1.0000x reference)
//
#include <hip/hip_runtime.h>
#include <cstdint>
#include <cstddef>

#define B_    2048
#define L_    13
#define H_    768
#define NROW  (B_ * L_)          // 26624 flattened hidden rows
#define RTEMP 20.0f              // 1 / 0.05
#define RS    768                // fp8 row stride bytes
#define NTILE 3328               // 16 M-panels x 208 N-panels (128x128 tiles)

typedef float f32x4 __attribute__((ext_vector_type(4)));

// ---- f32 -> OCP e4m3fn, RNE, saturating (no NaN/Inf inputs here) ----------
static __device__ __forceinline__ unsigned int f2e4m3(float f) {
  unsigned int u = __float_as_uint(f);
  unsigned int s = (u >> 24) & 0x80u;
  unsigned int ua = u & 0x7fffffffu;
  if (ua >= 0x43e80000u) return s | 0x7eu;          // >= 464 -> saturate 448
  if (ua < 0x3c800000u) {                           // < 2^-6: subnormal range
    int m = (int)rintf(__uint_as_float(ua) * 512.0f);   // 0..8 (8 -> 0x08 = 2^-6)
    return s | (unsigned int)m;
  }
  unsigned int lsb = (ua >> 20) & 1u;
  unsigned int r = ua + 0x7ffffu + lsb;             // RNE to 3 mantissa bits
  int Ee = (int)((r >> 23) & 0xffu) - 127;          // carry handled naturally
  unsigned int mant = (r >> 20) & 7u;
  return s | (unsigned int)(((Ee + 7) << 3) | mant);
}

__device__ __forceinline__ void llds16(const void* g, void* l) {
  __builtin_amdgcn_global_load_lds(
      (const __attribute__((address_space(1))) void*)g,
      (__attribute__((address_space(3))) void*)l, 16, 0, 0);
}

#define BAR do { asm volatile("" ::: "memory");            \
    __builtin_amdgcn_s_barrier();                          \
    asm volatile("" ::: "memory"); } while (0)

// ---------------------------------------------------------------------------
// Kernel 1: L2-normalize rows (f32 math), quantize to e4m3, LINEAR k layout
// (plain fp8 rows). One wave per row, 4 rows/block. Block 0 zeroes S_all/out.
// ---------------------------------------------------------------------------
__global__ __launch_bounds__(256) void k_normalize(
    const float* __restrict__ cls, const float* __restrict__ hidden,
    unsigned char* __restrict__ cn8, unsigned char* __restrict__ hn8,
    float* __restrict__ S_all, float* __restrict__ out)
{
  if (blockIdx.x == 0) {
#pragma unroll
    for (int i = 0; i < 8; ++i) S_all[threadIdx.x * 8 + i] = 0.0f;
    if (threadIdx.x == 0) *out = 0.0f;
  }

  const int wid = threadIdx.x >> 6, lane = threadIdx.x & 63;
  const int row = blockIdx.x * 4 + wid;
  const float4* src; unsigned char* dst;
  if (row < B_) { src = (const float4*)(cls + (size_t)row * H_);           dst = cn8 + (size_t)row * RS; }
  else          { src = (const float4*)(hidden + (size_t)(row - B_) * H_); dst = hn8 + (size_t)(row - B_) * RS; }

  float4 x0 = src[lane], x1 = src[lane + 64], x2 = src[lane + 128];
  float ss = x0.x*x0.x + x0.y*x0.y + x0.z*x0.z + x0.w*x0.w
           + x1.x*x1.x + x1.y*x1.y + x1.z*x1.z + x1.w*x1.w
           + x2.x*x2.x + x2.y*x2.y + x2.z*x2.z + x2.w*x2.w;
#pragma unroll
  for (int m = 1; m < 64; m <<= 1) ss += __shfl_xor(ss, m);
  const float sc = 1.0f / fmaxf(sqrtf(ss), 1e-8f);

  const int k = lane * 4;
  unsigned int p0 = f2e4m3(x0.x*sc) | (f2e4m3(x0.y*sc) << 8) | (f2e4m3(x0.z*sc) << 16) | (f2e4m3(x0.w*sc) << 24);
  unsigned int p1 = f2e4m3(x1.x*sc) | (f2e4m3(x1.y*sc) << 8) | (f2e4m3(x1.z*sc) << 16) | (f2e4m3(x1.w*sc) << 24);
  unsigned int p2 = f2e4m3(x2.x*sc) | (f2e4m3(x2.y*sc) << 8) | (f2e4m3(x2.z*sc) << 16) | (f2e4m3(x2.w*sc) << 24);
  *(unsigned int*)(dst + k)       = p0;
  *(unsigned int*)(dst + k + 256) = p1;
  *(unsigned int*)(dst + k + 512) = p2;
}

// ---------------------------------------------------------------------------
// Kernel 2: fp8 GEMM, UNIFORM DEPTH-3 PIPELINE at 16 waves/CU.
// BK=32 -> slot = A 4KB + B 4KB = 8KB; 5-slot ring = 40KB -> exactly
// 4 blocks/CU. Stage tile t+4 at step top (2 llds16/thread); counted
// vmcnt(6) at step end (t+1's loads landed; t+2..t+4 in flight, ~3 steps
// = >1000cy cover). 24 steps, inner 5-unroll makes slots static.
// LDS map (32B rows): 16B unit (row, kq) at line=row>>2,
// u = ((row&3)*2 + kq) ^ ((line>>1)&7) -> 2-way bank aliasing (free, m136).
// Read: addr = line*128 + u*16 + (q&1)*8, ds_read_b64 fragments.
// Decode (xcd=bid&7, M-inner), epilogue, 16x16x32 fp8 MFMA: R12-frozen.
// ---------------------------------------------------------------------------
__global__ __launch_bounds__(256, 4) void k_gemm(
    const unsigned char* __restrict__ cn8,
    const unsigned char* __restrict__ hn8,
    float* __restrict__ S_all,
    float* __restrict__ alignedD)
{
  __shared__ __align__(16) char lds[40960];   // 5 slots x (A 4KB | B 4KB)

  const int tid  = threadIdx.x;
  const int lane = tid & 63;
  const int wid  = tid >> 6;           // 0..3
  const int wm   = wid >> 1;           // 0..1  (M half: 64 rows)
  const int wn   = wid & 1;            // 0..1  (N half: 64 cols)
  const int fr   = lane & 15, q = lane >> 4;
  const int l4   = fr >> 2, c3 = fr & 3;

  // ---- fragment read offsets (verified forward/inverse on 4 cases) ------
  int offA[4], offB[4];
#pragma unroll
  for (int mi = 0; mi < 4; ++mi) {
    const int line = wm * 16 + mi * 4 + l4;
    const int hkey = (mi * 2 + (l4 >> 1)) & 7;
    const int u    = (c3 * 2 + (q >> 1)) ^ hkey;
    offA[mi] = line * 128 + u * 16 + (q & 1) * 8;
  }
#pragma unroll
  for (int ni = 0; ni < 4; ++ni) {
    const int line = wn * 16 + ni * 4 + l4;
    const int hkey = (ni * 2 + (l4 >> 1)) & 7;
    const int u    = (c3 * 2 + (q >> 1)) ^ hkey;
    offB[ni] = 4096 + line * 128 + u * 16 + (q & 1) * 8;
  }

  // ---- staging map (inverse of the unit map) -----------------------------
  const int sline = tid >> 3, su = tid & 7;
  const int sv    = su ^ ((sline >> 1) & 7);
  const int srow  = sline * 4 + (sv >> 1);    // 0..127
  const int skb   = (sv & 1) * 16;            // k-byte offset within row

  // R12 decode: 3328 = 8 XCD x (26 N x 16 M), M-inner within XCD.
  const int tile = blockIdx.x;
  const int xcd  = tile & 7;
  const int idx  = tile >> 3;
  const int brow = (idx & 15) << 7;
  const int bcol = (xcd * 26 + (idx >> 4)) << 7;

  const char* gA = (const char*)cn8 + (size_t)(brow + srow) * RS + skb;
  const char* gB = (const char*)hn8 + (size_t)(bcol + srow) * RS + skb;
  char* dA = lds + tid * 16;          // A region dest (within slot)
  char* dB = lds + 4096 + tid * 16;   // B region dest

#define STAGE(slotidx, koff) do {                                 \
    llds16(gA + (koff), dA + (slotidx) * 8192);                   \
    llds16(gB + (koff), dB + (slotidx) * 8192);                   \
  } while (0)

  f32x4 acc[4][4] = {};

#define DOSTEP(j, stagej, koff, wait) do {                        \
    if (stagej) STAGE((j + 4) % 5, koff);                         \
    const char* sb_ = lds + (j) * 8192;                           \
    long av[4], bv[4];                                            \
    _Pragma("unroll")                                             \
    for (int i = 0; i < 4; ++i) av[i] = *(const long*)(sb_ + offA[i]); \
    _Pragma("unroll")                                             \
    for (int i = 0; i < 4; ++i) bv[i] = *(const long*)(sb_ + offB[i]); \
    __builtin_amdgcn_s_setprio(1);                                \
    _Pragma("unroll")                                             \
    for (int mi = 0; mi < 4; ++mi)                                \
      _Pragma("unroll")                                           \
      for (int ni = 0; ni < 4; ++ni)                              \
        acc[mi][ni] = __builtin_amdgcn_mfma_f32_16x16x32_fp8_fp8( \
            av[mi], bv[ni], acc[mi][ni], 0, 0, 0);                \
    __builtin_amdgcn_s_setprio(0);                                \
    if (wait >= 0) {                                              \
      if (wait == 6) asm volatile("s_waitcnt vmcnt(6)" ::: "memory"); \
      else if (wait == 4) asm volatile("s_waitcnt vmcnt(4)" ::: "memory"); \
      else if (wait == 2) asm volatile("s_waitcnt vmcnt(2)" ::: "memory"); \
      else                asm volatile("s_waitcnt vmcnt(0)" ::: "memory"); \
      BAR;                                                        \
    }                                                             \
  } while (0)

  // prologue: tiles 0..3 -> slots 0..3 (8 loads); tile0 ready at vmcnt(6)
  STAGE(0, 0); STAGE(1, 32); STAGE(2, 64); STAGE(3, 96);
  asm volatile("s_waitcnt vmcnt(6)" ::: "memory");
  BAR;

  // main: t = 0..19 (4 outer x 5 static sub-steps); stage tile t+4
  for (int it = 0; it < 4; ++it) {
    DOSTEP(0, true, 4 * 32, 6);
    DOSTEP(1, true, 5 * 32, 6);
    DOSTEP(2, true, 6 * 32, 6);
    DOSTEP(3, true, 7 * 32, 6);
    DOSTEP(4, true, 8 * 32, 6);
    gA += 160; gB += 160;               // 5 tiles of 32B consumed
  }
  // tail: t = 20..23 (slots 0..3), no staging, draining counted waits
  DOSTEP(0, false, 0, 4);
  DOSTEP(1, false, 0, 2);
  DOSTEP(2, false, 0, 0);
  DOSTEP(3, false, 0, -1);

#undef DOSTEP
#undef STAGE

  // epilogue: row = brow+wm*64+mi*16+q*4+j, col = bcol+wn*64+ni*16+fr
  const int rowb = brow + wm * 64;
  const int colb = bcol + wn * 64;
#pragma unroll
  for (int mi = 0; mi < 4; ++mi) {
#pragma unroll
    for (int j = 0; j < 4; ++j) {
      const int grow = rowb + mi * 16 + q * 4 + j;
      float v = 0.f;
#pragma unroll
      for (int ni = 0; ni < 4; ++ni) {
        const int gcol = colb + ni * 16 + fr;
        const float a = acc[mi][ni][j];
        if ((unsigned)(gcol - grow * 13) < 13u) alignedD[gcol] = a;  // raw dot
        v += ((gcol & 2047) == grow) ? 0.f : __expf(RTEMP * a);     // masked sum
      }
      v += __shfl_xor(v, 1); v += __shfl_xor(v, 2);
      v += __shfl_xor(v, 4); v += __shfl_xor(v, 8);
      if (fr == 0) atomicAdd(&S_all[grow], v);
    }
  }
}

// ---------------------------------------------------------------------------
// Kernel 3: per row i: loss_i = sum_l [ log(exp(20 d_l) + s_i) - 20 d_l ].
// ---------------------------------------------------------------------------
__global__ __launch_bounds__(256) void k_finalize(
    const float* __restrict__ S_all, const float* __restrict__ alignedD,
    float* __restrict__ out)
{
  const int i = blockIdx.x * 256 + threadIdx.x;
  const int lane = threadIdx.x & 63, wid = threadIdx.x >> 6;
  const float s = S_all[i];
  float accv = 0.f;
#pragma unroll
  for (int l = 0; l < L_; l++) {
    const float d = RTEMP * alignedD[i * L_ + l];
    accv += logf(__expf(d) + s) - d;
  }
#pragma unroll
  for (int m = 1; m < 64; m <<= 1) accv += __shfl_xor(accv, m);
  __shared__ float wsum[4];
  if (lane == 0) wsum[wid] = accv;
  __syncthreads();
  if (threadIdx.x == 0)
    atomicAdd(out, (wsum[0] + wsum[1] + wsum[2] + wsum[3]) * (1.0f / (float)(B_ * L_)));
}

// ---------------------------------------------------------------------------
extern "C" void kernel_launch(void* const* d_in, const int* in_sizes, int n_in,
                              void* d_out, int out_size, void* d_ws, size_t ws_size,
                              hipStream_t stream) {
  const float* cls    = (const float*)d_in[0];
  const float* hidden = (const float*)d_in[1];
  float* out = (float*)d_out;

  // ws: hn8 (20,447,232) | cn8 (1,572,864) | S_all (8,192) | alignedD (106,496)
  char* ws = (char*)d_ws;
  unsigned char* hn8 = (unsigned char*)ws;
  unsigned char* cn8 = (unsigned char*)(ws + (size_t)NROW * RS);
  float* S_all    = (float*)(ws + (size_t)NROW * RS + (size_t)B_ * RS);
  float* alignedD = (float*)(ws + (size_t)NROW * RS + (size_t)B_ * RS + B_ * sizeof(float));

  k_normalize<<<(B_ + NROW) / 4, 256, 0, stream>>>(cls, hidden, cn8, hn8, S_all, out);
  k_gemm<<<NTILE, 256, 0, stream>>>(cn8, hn8, S_all, alignedD);
  k_finalize<<<B_ / 256, 256, 0, stream>>>(S_all, alignedD, out);
}